// Round 1
// baseline (473.886 us; speedup 1.0000x reference)
//
#include <hip/hip_runtime.h>

// ---------------------------------------------------------------------------
// Fused self-attention, B=8 N=4096 D=256, f32 in/out, bf16 MFMA internally.
// ws layout: Qs bf16 [B*N][256] @0 (Q pre-scaled by log2e/16)
//            Kb bf16 [B*N][256] @16MB
//            VT bf16 [B][256][N] @32MB   (V transposed for PV B-fragments)
// ---------------------------------------------------------------------------

typedef __attribute__((ext_vector_type(8))) short short8;   // 8 bf16 = 4 VGPR
typedef __attribute__((ext_vector_type(4))) float f32x4;

#define MFMA16(A, B, C) __builtin_amdgcn_mfma_f32_16x16x32_bf16(A, B, C, 0, 0, 0)

__device__ __forceinline__ unsigned short f2bf(float f) {
  union { float f; unsigned u; } v; v.f = f;
  unsigned r = v.u + 0x7FFFu + ((v.u >> 16) & 1u);   // RNE
  return (unsigned short)(r >> 16);
}

__device__ __forceinline__ short8 load8_f32_bf16(const float* p) {
  const float4* q = (const float4*)p;
  float4 a = q[0], b = q[1];
  short8 r;
  r[0] = (short)f2bf(a.x); r[1] = (short)f2bf(a.y);
  r[2] = (short)f2bf(a.z); r[3] = (short)f2bf(a.w);
  r[4] = (short)f2bf(b.x); r[5] = (short)f2bf(b.y);
  r[6] = (short)f2bf(b.z); r[7] = (short)f2bf(b.w);
  return r;
}

__device__ __forceinline__ void gload_lds16(const void* g, void* l) {
  __builtin_amdgcn_global_load_lds(
      (const __attribute__((address_space(1))) void*)g,
      (__attribute__((address_space(3))) void*)l, 16, 0, 0);
}

// --------------------------- QK projection --------------------------------
// out[tok][e] = x[tok]·W[e] + b[e]; e<256 -> Q (scaled), 256<=e<512 -> K.
__global__ __launch_bounds__(256)
void qk_proj_kernel(const float* __restrict__ x, const float* __restrict__ W,
                    const float* __restrict__ bias,
                    unsigned short* __restrict__ Qs,
                    unsigned short* __restrict__ Kb) {
  const int tid = threadIdx.x;
  const int wid = tid >> 6, lane = tid & 63, l15 = lane & 15, lhi = lane >> 4;
  const int e0   = blockIdx.x * 64;            // 0..448 (e in [0,512))
  const int tok0 = blockIdx.y * 64 + wid * 16; // 16 tokens per wave

  const float* arow = x + (size_t)(tok0 + l15) * 256 + lhi * 8;
  f32x4 acc[4];
#pragma unroll
  for (int i = 0; i < 4; ++i) acc[i] = (f32x4){0.f, 0.f, 0.f, 0.f};

#pragma unroll
  for (int ks = 0; ks < 8; ++ks) {
    short8 af = load8_f32_bf16(arow + ks * 32);   // A: x[tok=l15][k contig]
#pragma unroll
    for (int et = 0; et < 4; ++et) {              // B: W[e=l15][k contig]
      short8 bf = load8_f32_bf16(W + (size_t)(e0 + et * 16 + l15) * 256 + ks * 32 + lhi * 8);
      acc[et] = MFMA16(af, bf, acc[et]);
    }
  }

  const float QSC = 0.0901684400555602f;  // log2(e)/16
#pragma unroll
  for (int et = 0; et < 4; ++et) {
    int e = e0 + et * 16 + l15;
    float bv = bias[e];
#pragma unroll
    for (int r = 0; r < 4; ++r) {
      int tok = tok0 + lhi * 4 + r;               // D: row=(lane>>4)*4+reg
      float val = acc[et][r] + bv;
      if (e < 256) Qs[(size_t)tok * 256 + e] = f2bf(val * QSC);
      else         Kb[(size_t)tok * 256 + (e - 256)] = f2bf(val);
    }
  }
}

// --------------------------- V projection (transposed out) ----------------
// VT[b][d][n] = x[tok]·W[512+d] + b[512+d]; computed as W_v · x^T so the
// accumulator is [d][token] and stores are token-contiguous.
__global__ __launch_bounds__(256)
void v_proj_kernel(const float* __restrict__ x, const float* __restrict__ W,
                   const float* __restrict__ bias,
                   unsigned short* __restrict__ VT) {
  const int tid = threadIdx.x;
  const int wid = tid >> 6, lane = tid & 63, l15 = lane & 15, lhi = lane >> 4;
  const int ep0 = blockIdx.x * 64 + wid * 16;  // 16 V-dims per wave
  const int t0  = blockIdx.y * 64;             // 64 tokens per block

  const float* arow = W + (size_t)(512 + ep0 + l15) * 256 + lhi * 8;
  f32x4 acc[4];
#pragma unroll
  for (int i = 0; i < 4; ++i) acc[i] = (f32x4){0.f, 0.f, 0.f, 0.f};

#pragma unroll
  for (int ks = 0; ks < 8; ++ks) {
    short8 af = load8_f32_bf16(arow + ks * 32);   // A: W_v[d=l15][k contig]
#pragma unroll
    for (int et = 0; et < 4; ++et) {              // B: x[tok=l15][k contig]
      short8 bf = load8_f32_bf16(x + (size_t)(t0 + et * 16 + l15) * 256 + ks * 32 + lhi * 8);
      acc[et] = MFMA16(af, bf, acc[et]);
    }
  }

#pragma unroll
  for (int r = 0; r < 4; ++r) {
    int ep = ep0 + lhi * 4 + r;                  // D row = V dim
    float bv = bias[512 + ep];
#pragma unroll
    for (int et = 0; et < 4; ++et) {
      int tok = t0 + et * 16 + l15;              // D col = token
      int b = tok >> 12, n = tok & 4095;
      VT[(size_t)b * (256 * 4096) + (size_t)ep * 4096 + n] = f2bf(acc[et][r] + bv);
    }
  }
}

// --------------------------- Flash attention ------------------------------
// Grid 512 = 8 batches * 64 q-blocks; batch = blk&7 pins each batch to one XCD.
// Block: 4 waves * 16 q-rows = QB 64. KV tiles of 64 rows, single-buffered LDS.
__global__ __launch_bounds__(256, 2)
void attn_kernel(const unsigned short* __restrict__ Qs,
                 const unsigned short* __restrict__ Kb,
                 const unsigned short* __restrict__ VT,
                 float* __restrict__ out) {
  // K tile [64][256] bf16 (rows 512B, 32 granules of 16B, XOR-swizzled)
  __shared__ __align__(16) unsigned short lds_k[64 * 256];
  // VT tile [256][64] bf16 (rows 128B, 8 granules, XOR-swizzled)
  __shared__ __align__(16) unsigned short lds_vt[256 * 64];
  // P per-wave [16][64] bf16 (rows 128B, swizzled)
  __shared__ __align__(16) unsigned short lds_p[4 * 16 * 64];

  const int tid = threadIdx.x;
  const int wid = tid >> 6, lane = tid & 63, l15 = lane & 15, lhi = lane >> 4;
  const int blk = blockIdx.x;
  const int b = blk & 7;          // batch -> XCD pinning
  const int qblk = blk >> 3;      // 0..63

  // Q fragments, held for the whole kernel: Q[q=l15][k contig], 8 k-steps
  const unsigned short* qptr =
      Qs + ((size_t)b * 4096 + qblk * 64 + wid * 16 + l15) * 256 + lhi * 8;
  short8 qf[8];
#pragma unroll
  for (int ks = 0; ks < 8; ++ks) qf[ks] = *(const short8*)(qptr + ks * 32);

  f32x4 acco[16];
#pragma unroll
  for (int dt = 0; dt < 16; ++dt) acco[dt] = (f32x4){0.f, 0.f, 0.f, 0.f};
  float m_run[4] = {-1e30f, -1e30f, -1e30f, -1e30f};
  float l_run[4] = {0.f, 0.f, 0.f, 0.f};

  const unsigned short* kbase = Kb + (size_t)b * 4096 * 256;
  const unsigned short* vtb   = VT + (size_t)b * 256 * 4096;

  for (int kv = 0; kv < 64; ++kv) {
    const int kv0 = kv * 64;
    // ---- stage K tile (contiguous 32KB), source pre-swizzled ----
    {
      const unsigned short* src = kbase + (size_t)kv0 * 256;
#pragma unroll
      for (int i = 0; i < 8; ++i) {
        int g = i * 256 + tid;                 // dest granule for this lane
        int row = g >> 5, cp = g & 31;
        int sg = (row << 5) | (cp ^ (row & 7));
        gload_lds16(src + sg * 8, &lds_k[(i * 256 + (wid << 6)) * 8]);
      }
      // ---- stage VT tile (strided rows of 128B) ----
#pragma unroll
      for (int i = 0; i < 8; ++i) {
        int g = i * 256 + tid;
        int d = g >> 3, cp = g & 7;
        int sc = cp ^ (d & 7);
        gload_lds16(vtb + (size_t)d * 4096 + kv0 + sc * 8,
                    &lds_vt[(i * 256 + (wid << 6)) * 8]);
      }
    }
    asm volatile("s_waitcnt vmcnt(0)" ::: "memory");
    __syncthreads();

    // ---- S = Q·K^T (pre-scaled by log2e/16 via Q) ----
    f32x4 accs[4];
#pragma unroll
    for (int i = 0; i < 4; ++i) accs[i] = (f32x4){0.f, 0.f, 0.f, 0.f};
#pragma unroll
    for (int ks = 0; ks < 8; ++ks) {
#pragma unroll
      for (int tt = 0; tt < 4; ++tt) {
        int krow = tt * 16 + l15;
        int c = ks * 4 + lhi;
        short8 kf = *(const short8*)&lds_k[krow * 256 + ((c ^ (krow & 7)) << 3)];
        accs[tt] = MFMA16(qf[ks], kf, accs[tt]);
      }
    }

    // ---- online softmax (rows r live on all 16 lanes of each lhi group) ----
    float al[4];
#pragma unroll
    for (int r = 0; r < 4; ++r) {
      float m0 = fmaxf(fmaxf(accs[0][r], accs[1][r]), fmaxf(accs[2][r], accs[3][r]));
#pragma unroll
      for (int sh = 1; sh < 16; sh <<= 1) m0 = fmaxf(m0, __shfl_xor(m0, sh));
      float mn = fmaxf(m_run[r], m0);
      al[r] = __builtin_amdgcn_exp2f(m_run[r] - mn);
      m_run[r] = mn;
      float rs = 0.f;
#pragma unroll
      for (int tt = 0; tt < 4; ++tt) {
        float p = __builtin_amdgcn_exp2f(accs[tt][r] - mn);
        accs[tt][r] = p;
        rs += p;
      }
#pragma unroll
      for (int sh = 1; sh < 16; sh <<= 1) rs += __shfl_xor(rs, sh);
      l_run[r] = l_run[r] * al[r] + rs;
    }
#pragma unroll
    for (int dt = 0; dt < 16; ++dt) {
#pragma unroll
      for (int r = 0; r < 4; ++r) acco[dt][r] *= al[r];
    }

    // ---- P -> per-wave LDS (swizzled rows of 128B) ----
#pragma unroll
    for (int tt = 0; tt < 4; ++tt) {
      int cg = (l15 >> 3) + tt * 2;   // col granule of col = l15 + 16*tt
      int cl = l15 & 7;
#pragma unroll
      for (int r = 0; r < 4; ++r) {
        int q = lhi * 4 + r;
        lds_p[wid * 1024 + q * 64 + ((cg ^ (q & 7)) << 3) + cl] = f2bf(accs[tt][r]);
      }
    }

    // ---- PV: acco += P · V  (A=P[q=l15][m contig], B=VT[d=l15][m contig]) ----
#pragma unroll
    for (int kt = 0; kt < 2; ++kt) {
      int cgp = lhi + kt * 4;
      short8 pf = *(const short8*)&lds_p[wid * 1024 + l15 * 64 + ((cgp ^ (l15 & 7)) << 3)];
#pragma unroll
      for (int dt = 0; dt < 16; ++dt) {
        int d = dt * 16 + l15;
        short8 vf = *(const short8*)&lds_vt[d * 64 + ((cgp ^ (d & 7)) << 3)];
        acco[dt] = MFMA16(pf, vf, acco[dt]);
      }
    }
    __syncthreads();   // everyone done reading lds_k/lds_vt before next stage
  }

  float inv[4];
#pragma unroll
  for (int r = 0; r < 4; ++r) inv[r] = 1.f / l_run[r];
  float* orow = out + ((size_t)b * 4096 + qblk * 64 + wid * 16) * 256;
#pragma unroll
  for (int dt = 0; dt < 16; ++dt) {
#pragma unroll
    for (int r = 0; r < 4; ++r)
      orow[(size_t)(lhi * 4 + r) * 256 + dt * 16 + l15] = acco[dt][r] * inv[r];
  }
}

// ---------------------------------------------------------------------------
extern "C" void kernel_launch(void* const* d_in, const int* in_sizes, int n_in,
                              void* d_out, int out_size, void* d_ws, size_t ws_size,
                              hipStream_t stream) {
  const float* x    = (const float*)d_in[0];   // [8,4096,256]
  const float* W    = (const float*)d_in[1];   // [768,256]
  const float* bias = (const float*)d_in[2];   // [768]
  float* out = (float*)d_out;                  // [8,4096,256] f32

  char* ws = (char*)d_ws;
  unsigned short* Qs = (unsigned short*)(ws);                              // 16MB
  unsigned short* Kb = (unsigned short*)(ws + (size_t)16 * 1024 * 1024);   // 16MB
  unsigned short* VT = (unsigned short*)(ws + (size_t)32 * 1024 * 1024);   // 16MB

  qk_proj_kernel<<<dim3(8, 512), 256, 0, stream>>>(x, W, bias, Qs, Kb);
  v_proj_kernel<<<dim3(4, 512), 256, 0, stream>>>(x, W, bias, VT);
  attn_kernel<<<512, 256, 0, stream>>>(Qs, Kb, VT, out);
}

// Round 3
// 352.829 us; speedup vs baseline: 1.3431x; 1.3431x over previous
//
#include <hip/hip_runtime.h>

// ---------------------------------------------------------------------------
// Fused self-attention, B=8 N=4096 D=256, f32 in/out, bf16 MFMA internally.
// ws: Qs bf16 [B*N][256] @0 (pre-scaled by log2e/16)
//     Kb bf16 [B*N][256] @16MB
//     VT bf16 [B][256][N] @32MB
// ---------------------------------------------------------------------------

typedef __attribute__((ext_vector_type(8))) short short8;   // 8 bf16 = 4 VGPR
typedef __attribute__((ext_vector_type(4))) float f32x4;

#define MFMA16(A, B, C) __builtin_amdgcn_mfma_f32_16x16x32_bf16(A, B, C, 0, 0, 0)

__device__ __forceinline__ unsigned short f2bf(float f) {
  union { float f; unsigned u; } v; v.f = f;
  unsigned r = v.u + 0x7FFFu + ((v.u >> 16) & 1u);   // RNE
  return (unsigned short)(r >> 16);
}

__device__ __forceinline__ ushort4 pack4(float4 v) {
  ushort4 r;
  r.x = f2bf(v.x); r.y = f2bf(v.y); r.z = f2bf(v.z); r.w = f2bf(v.w);
  return r;
}

__device__ __forceinline__ void gload_lds16(const void* g, void* l) {
  __builtin_amdgcn_global_load_lds(
      (const __attribute__((address_space(1))) void*)g,
      (__attribute__((address_space(3))) void*)l, 16, 0, 0);
}

// DPP rotate within 16-lane rows (VALU, keeps reductions off the LDS pipe).
// ctrl must be a literal -> template parameter.
template <int CTRL>
__device__ __forceinline__ float dpp_ror(float x) {
  return __int_as_float(
      __builtin_amdgcn_update_dpp(0, __float_as_int(x), CTRL, 0xf, 0xf, true));
}
__device__ __forceinline__ float red16_max(float x) {
  x = fmaxf(x, dpp_ror<0x128>(x));  // row_ror:8
  x = fmaxf(x, dpp_ror<0x124>(x));  // row_ror:4
  x = fmaxf(x, dpp_ror<0x122>(x));  // row_ror:2
  x = fmaxf(x, dpp_ror<0x121>(x));  // row_ror:1
  return x;
}
__device__ __forceinline__ float red16_sum(float x) {
  x += dpp_ror<0x128>(x);
  x += dpp_ror<0x124>(x);
  x += dpp_ror<0x122>(x);
  x += dpp_ror<0x121>(x);
  return x;
}

// --------------------------- Projection GEMM ------------------------------
// C[m][n] = A[m]·B[n] (+bias); 128x128 tile, BK=64, 4 waves each [32 m][128 n].
// MODE 0: A=x(tok), B=W(e<512) -> Qs (scaled) / Kb.   grid (4, 256)
// MODE 1: A=W+512 (d), B=x(tok) -> VT[b][d][n].       grid (2, 256)
template <int MODE>
__global__ __launch_bounds__(256)
void proj_kernel(const float* __restrict__ A, const float* __restrict__ Bm,
                 const float* __restrict__ bias,
                 unsigned short* __restrict__ Qs, unsigned short* __restrict__ Kb,
                 unsigned short* __restrict__ VT) {
  __shared__ __align__(16) unsigned short as_[2][128 * 64];
  __shared__ __align__(16) unsigned short bs_[2][128 * 64];

  const int tid = threadIdx.x;
  const int wid = tid >> 6, lane = tid & 63, l15 = lane & 15, lhi = lane >> 4;
  int m0, n0;
  if (MODE == 0) { m0 = blockIdx.y * 128; n0 = blockIdx.x * 128; }
  else           { m0 = blockIdx.x * 128; n0 = blockIdx.y * 128; }
  const float* Arow = A + (size_t)m0 * 256;
  const float* Brow = Bm + (size_t)n0 * 256;

  const int srow = tid >> 4;      // staging row-within-16
  const int c4 = tid & 15;        // staging float4 column
  float4 ra[8], rb[8];

  auto loadslice = [&](int kc) {
#pragma unroll
    for (int i = 0; i < 8; ++i) {
      int row = i * 16 + srow;
      ra[i] = *(const float4*)(Arow + (size_t)row * 256 + kc * 64 + c4 * 4);
      rb[i] = *(const float4*)(Brow + (size_t)row * 256 + kc * 64 + c4 * 4);
    }
  };
  auto writeslice = [&](int buf) {
#pragma unroll
    for (int i = 0; i < 8; ++i) {
      int row = i * 16 + srow;
      int g = c4 >> 1, half = c4 & 1;
      int off = row * 64 + ((g ^ (row & 7)) << 3) + half * 4;
      *(ushort4*)&as_[buf][off] = pack4(ra[i]);
      *(ushort4*)&bs_[buf][off] = pack4(rb[i]);
    }
  };

  f32x4 acc[2][8];
#pragma unroll
  for (int mt = 0; mt < 2; ++mt)
#pragma unroll
    for (int nt = 0; nt < 8; ++nt) acc[mt][nt] = (f32x4){0.f, 0.f, 0.f, 0.f};

  loadslice(0);
  writeslice(0);
  int cur = 0;
  for (int kc = 0; kc < 4; ++kc) {
    __syncthreads();
    if (kc < 3) loadslice(kc + 1);
#pragma unroll
    for (int ks = 0; ks < 2; ++ks) {
      short8 af[2];
#pragma unroll
      for (int mt = 0; mt < 2; ++mt) {
        int row = wid * 32 + mt * 16 + l15;
        int g = ks * 4 + lhi;
        af[mt] = *(const short8*)&as_[cur][row * 64 + ((g ^ (row & 7)) << 3)];
      }
#pragma unroll
      for (int nt = 0; nt < 8; ++nt) {
        int row = nt * 16 + l15;
        int g = ks * 4 + lhi;
        short8 bf = *(const short8*)&bs_[cur][row * 64 + ((g ^ (row & 7)) << 3)];
        acc[0][nt] = MFMA16(af[0], bf, acc[0][nt]);
        acc[1][nt] = MFMA16(af[1], bf, acc[1][nt]);
      }
    }
    if (kc < 3) writeslice(cur ^ 1);
    cur ^= 1;
  }

  const float QSC = 0.0901684400555602f;  // log2(e)/16
#pragma unroll
  for (int nt = 0; nt < 8; ++nt) {
    if (MODE == 0) {
      int e = n0 + nt * 16 + l15;
      float bv = bias[e];
#pragma unroll
      for (int mt = 0; mt < 2; ++mt)
#pragma unroll
        for (int r = 0; r < 4; ++r) {
          int tok = m0 + wid * 32 + mt * 16 + lhi * 4 + r;
          float val = acc[mt][nt][r] + bv;
          if (e < 256) Qs[(size_t)tok * 256 + e] = f2bf(val * QSC);
          else         Kb[(size_t)tok * 256 + (e - 256)] = f2bf(val);
        }
    } else {
      int tok = n0 + nt * 16 + l15;
      int bb = tok >> 12, n = tok & 4095;
#pragma unroll
      for (int mt = 0; mt < 2; ++mt)
#pragma unroll
        for (int r = 0; r < 4; ++r) {
          int d = m0 + wid * 32 + mt * 16 + lhi * 4 + r;
          float val = acc[mt][nt][r] + bias[512 + d];
          VT[(size_t)bb * (256 * 4096) + (size_t)d * 4096 + n] = f2bf(val);
        }
    }
  }
}

// --------------------------- Flash attention ------------------------------
// Grid 256 = 8 batches * 32 q-blocks (batch = blk&7 -> XCD pin, KV L2-resident).
// Block: 4 waves * 32 q-rows = QB 128; KV tiles of 64, double-buffered LDS.
// Per wave M_tiles=2 -> every K/V LDS fragment feeds 2 MFMAs.
__global__ __launch_bounds__(256, 1)
void attn_kernel(const unsigned short* __restrict__ Qs,
                 const unsigned short* __restrict__ Kb,
                 const unsigned short* __restrict__ VT,
                 float* __restrict__ out) {
  __shared__ __align__(16) unsigned short lds_k[2 * 64 * 256];   // 64KB
  __shared__ __align__(16) unsigned short lds_vt[2 * 256 * 64];  // 64KB
  __shared__ __align__(16) unsigned short lds_p[4 * 32 * 64];    // 16KB

  const int tid = threadIdx.x;
  const int wid = tid >> 6, lane = tid & 63, l15 = lane & 15, lhi = lane >> 4;
  const int blk = blockIdx.x;
  const int b = blk & 7;
  const int qblk = blk >> 3;                 // 0..31
  const int q0 = qblk * 128 + wid * 32;

  // Q fragments [mt][ks], held all kernel: Q[q=l15][k contig]
  short8 qf[2][8];
#pragma unroll
  for (int mt = 0; mt < 2; ++mt) {
    const unsigned short* qptr =
        Qs + ((size_t)b * 4096 + q0 + mt * 16 + l15) * 256 + lhi * 8;
#pragma unroll
    for (int ks = 0; ks < 8; ++ks) qf[mt][ks] = *(const short8*)(qptr + ks * 32);
  }

  f32x4 acco[2][16];
#pragma unroll
  for (int mt = 0; mt < 2; ++mt)
#pragma unroll
    for (int dt = 0; dt < 16; ++dt) acco[mt][dt] = (f32x4){0.f, 0.f, 0.f, 0.f};
  float m_run[2][4], l_run[2][4];
#pragma unroll
  for (int mt = 0; mt < 2; ++mt)
#pragma unroll
    for (int r = 0; r < 4; ++r) { m_run[mt][r] = -1e30f; l_run[mt][r] = 0.f; }

  const unsigned short* kbase = Kb + (size_t)b * 4096 * 256;
  const unsigned short* vtb   = VT + (size_t)b * 256 * 4096;

  auto stage = [&](int kv0, int buf) {
    unsigned short* kbuf = lds_k + buf * 16384;
    unsigned short* vbuf = lds_vt + buf * 16384;
    const unsigned short* src = kbase + (size_t)kv0 * 256;
#pragma unroll
    for (int i = 0; i < 8; ++i) {
      int g = i * 256 + tid;
      int row = g >> 5, cp = g & 31;
      int sg = (row << 5) | (cp ^ (row & 7));
      gload_lds16(src + sg * 8, kbuf + (i * 256 + (wid << 6)) * 8);
    }
#pragma unroll
    for (int i = 0; i < 8; ++i) {
      int g = i * 256 + tid;
      int d = g >> 3, cp = g & 7;
      int sc = cp ^ (d & 7);
      gload_lds16(vtb + (size_t)d * 4096 + kv0 + sc * 8,
                  vbuf + (i * 256 + (wid << 6)) * 8);
    }
  };

  stage(0, 0);
  int cur = 0;
  for (int kv = 0; kv < 64; ++kv) {
    __syncthreads();   // implicit vmcnt(0): buf[cur] staged; buf[cur^1] readers done
    if (kv < 63) stage((kv + 1) * 64, cur ^ 1);
    const unsigned short* kb = lds_k + cur * 16384;
    const unsigned short* vb = lds_vt + cur * 16384;

    // ---- S = Q·K^T (scale folded into Q) ----
    f32x4 accs[2][4];
#pragma unroll
    for (int mt = 0; mt < 2; ++mt)
#pragma unroll
      for (int tt = 0; tt < 4; ++tt) accs[mt][tt] = (f32x4){0.f, 0.f, 0.f, 0.f};
#pragma unroll
    for (int ks = 0; ks < 8; ++ks) {
#pragma unroll
      for (int tt = 0; tt < 4; ++tt) {
        int krow = tt * 16 + l15;
        int c = ks * 4 + lhi;
        short8 kf = *(const short8*)&kb[krow * 256 + ((c ^ (krow & 7)) << 3)];
        accs[0][tt] = MFMA16(qf[0][ks], kf, accs[0][tt]);
        accs[1][tt] = MFMA16(qf[1][ks], kf, accs[1][tt]);
      }
    }

    // ---- online softmax (DPP row reductions; defer-max THR=4 log2-units) ----
    float al[2][4];
    bool resc = false;
#pragma unroll
    for (int mt = 0; mt < 2; ++mt)
#pragma unroll
      for (int r = 0; r < 4; ++r) {
        float mx = fmaxf(fmaxf(accs[mt][0][r], accs[mt][1][r]),
                         fmaxf(accs[mt][2][r], accs[mt][3][r]));
        mx = red16_max(mx);
        float mo = m_run[mt][r];
        float mn = (mx > mo + 4.0f) ? mx : mo;
        al[mt][r] = __builtin_amdgcn_exp2f(mo - mn);
        m_run[mt][r] = mn;
        float rs = 0.f;
#pragma unroll
        for (int tt = 0; tt < 4; ++tt) {
          float p = __builtin_amdgcn_exp2f(accs[mt][tt][r] - mn);
          accs[mt][tt][r] = p;
          rs += p;
        }
        rs = red16_sum(rs);
        l_run[mt][r] = l_run[mt][r] * al[mt][r] + rs;
        resc |= (mn != mo);
      }
    if (__any(resc)) {
#pragma unroll
      for (int mt = 0; mt < 2; ++mt)
#pragma unroll
        for (int dt = 0; dt < 16; ++dt)
#pragma unroll
          for (int r = 0; r < 4; ++r) acco[mt][dt][r] *= al[mt][r];
    }

    // ---- P -> per-wave LDS (swizzled 128B rows) ----
#pragma unroll
    for (int mt = 0; mt < 2; ++mt)
#pragma unroll
      for (int tt = 0; tt < 4; ++tt) {
        int cg = (l15 >> 3) + tt * 2;
        int cl = l15 & 7;
#pragma unroll
        for (int r = 0; r < 4; ++r) {
          int q = mt * 16 + lhi * 4 + r;
          lds_p[wid * 2048 + q * 64 + ((cg ^ (q & 7)) << 3) + cl] =
              f2bf(accs[mt][tt][r]);
        }
      }

    // ---- PV: each V fragment feeds 2 MFMAs ----
#pragma unroll
    for (int kt = 0; kt < 2; ++kt) {
      int cgp = lhi + kt * 4;
      int swl = (cgp ^ (l15 & 7)) << 3;
      short8 pf0 = *(const short8*)&lds_p[wid * 2048 + l15 * 64 + swl];
      short8 pf1 = *(const short8*)&lds_p[wid * 2048 + (16 + l15) * 64 + swl];
#pragma unroll
      for (int dt = 0; dt < 16; ++dt) {
        int d = dt * 16 + l15;
        short8 vf = *(const short8*)&vb[d * 64 + ((cgp ^ (d & 7)) << 3)];
        acco[0][dt] = MFMA16(pf0, vf, acco[0][dt]);
        acco[1][dt] = MFMA16(pf1, vf, acco[1][dt]);
      }
    }
    cur ^= 1;
  }

  float inv[2][4];
#pragma unroll
  for (int mt = 0; mt < 2; ++mt)
#pragma unroll
    for (int r = 0; r < 4; ++r) inv[mt][r] = 1.f / l_run[mt][r];
  float* orow = out + ((size_t)b * 4096 + q0) * 256;
#pragma unroll
  for (int mt = 0; mt < 2; ++mt)
#pragma unroll
    for (int dt = 0; dt < 16; ++dt)
#pragma unroll
      for (int r = 0; r < 4; ++r)
        orow[(size_t)(mt * 16 + lhi * 4 + r) * 256 + dt * 16 + l15] =
            acco[mt][dt][r] * inv[mt][r];
}

// ---------------------------------------------------------------------------
extern "C" void kernel_launch(void* const* d_in, const int* in_sizes, int n_in,
                              void* d_out, int out_size, void* d_ws, size_t ws_size,
                              hipStream_t stream) {
  const float* x    = (const float*)d_in[0];   // [8,4096,256]
  const float* W    = (const float*)d_in[1];   // [768,256]
  const float* bias = (const float*)d_in[2];   // [768]
  float* out = (float*)d_out;                  // [8,4096,256] f32

  char* ws = (char*)d_ws;
  unsigned short* Qs = (unsigned short*)(ws);
  unsigned short* Kb = (unsigned short*)(ws + (size_t)16 * 1024 * 1024);
  unsigned short* VT = (unsigned short*)(ws + (size_t)32 * 1024 * 1024);

  proj_kernel<0><<<dim3(4, 256), 256, 0, stream>>>(x, W, bias, Qs, Kb, VT);
  proj_kernel<1><<<dim3(2, 256), 256, 0, stream>>>(W + 512 * 256, x, bias, Qs, Kb, VT);
  attn_kernel<<<256, 256, 0, stream>>>(Qs, Kb, VT, out);
}